// Round 1
// baseline (99.781 us; speedup 1.0000x reference)
//
#include <hip/hip_runtime.h>
#include <hip/hip_bf16.h>

// PraxisMemory: one-shot delta-rule memory. B=4,H=16,S=4096,D=64, all f32 I/O.
// k1: per (b,h, S-chunk) compute partial M = sigma_k^T @ (V - (sigma_k@W0)/(sigma_k.z0)),
//     partial z = colsum(sigma_k). k_reduce: sum partials + init. k2: out = blend.

#define B_  4
#define H_  16
#define S_  4096
#define D_  64
#define BH_ 64
#define EPS_ 1e-8f

typedef __attribute__((ext_vector_type(8))) short bf16x8;
typedef __attribute__((ext_vector_type(4))) float f32x4;

__device__ __forceinline__ unsigned short f2bf(float x) {
    union { float f; unsigned u; } v; v.f = x;
    return (unsigned short)((v.u + 0x7FFFu + ((v.u >> 16) & 1u)) >> 16);  // RTNE
}
__device__ __forceinline__ float elup1(float x) {
    // elu(x)+1 = x+1 (x>0) else exp(x)
    return x > 0.0f ? x + 1.0f : __expf(x);
}
__device__ __forceinline__ f32x4 fzero() { f32x4 z = {0.f, 0.f, 0.f, 0.f}; return z; }

// ---------------------------------------------------------------------------
// Kernel 1: per-(bh, split) partial states.
// Layouts (16x16x32 bf16 MFMA):
//   A-frag: lane l -> m = l&15, k at (g,j) with g=l>>4, j=0..7 (any consistent bijection OK)
//   B-frag: lane l -> n = l&15, same (g,j)->k
//   C/D:    lane l, reg r -> row m=(l>>4)*4+r, col n=l&15   [verified layout]
// GEMM1 computed transposed: NUM^T = W0^T @ SK^T  => den & V align per-lane, float4 V loads.
// GEMM2: MP += SK^T @ VU via per-wave LDS transpose buffers (packed b32 writes, b128 reads).
// k-column permutation in LDS: short-col c = 2*(l&15) + stile  <->  s = (c&1)*16 + (c>>1),
// identical for A and B operands, hence legal.
// ---------------------------------------------------------------------------
__global__ __launch_bounds__(256, 2) void k1_states(
    const float* __restrict__ Kp, const float* __restrict__ Vp,
    const float* __restrict__ W0, const float* __restrict__ Z0,
    float* __restrict__ Mpart, float* __restrict__ Zpart, int NS)
{
    const int bh = blockIdx.x / NS;
    const int p  = blockIdx.x % NS;
    const int h  = bh & (H_ - 1);
    const int tid  = threadIdx.x;
    const int lane = tid & 63;
    const int wave = tid >> 6;
    const int c16  = lane & 15;
    const int g4   = lane >> 4;

    // per-wave transpose slabs: [64 rows][40 shorts] (pitch 80B -> 16B-aligned b128 reads)
    __shared__ __align__(16) unsigned short skT[4][64][40];
    __shared__ __align__(16) unsigned short vuT[4][64][40];
    __shared__ float Mlds[64 * 65];
    __shared__ float Zlds[4][64];

    // z0 per-lane: z0v[kk][j] = Z0[h, kk*32 + g4*8 + j]
    float z0v[2][8];
    #pragma unroll
    for (int kk = 0; kk < 2; ++kk) {
        f32x4 a = *(const f32x4*)(Z0 + h * 64 + kk * 32 + g4 * 8);
        f32x4 b = *(const f32x4*)(Z0 + h * 64 + kk * 32 + g4 * 8 + 4);
        #pragma unroll
        for (int j = 0; j < 4; ++j) { z0v[kk][j] = a[j]; z0v[kk][4 + j] = b[j]; }
    }

    // W0^T A-fragments: A[e][d] = W0[d][e]; built once per block
    bf16x8 w0f[4][2];
    #pragma unroll
    for (int et = 0; et < 4; ++et)
    #pragma unroll
    for (int kk = 0; kk < 2; ++kk) {
        bf16x8 f;
        #pragma unroll
        for (int j = 0; j < 8; ++j) {
            int d = kk * 32 + g4 * 8 + j;
            f[j] = (short)f2bf(W0[(size_t)h * 4096 + d * 64 + et * 16 + c16]);
        }
        w0f[et][kk] = f;
    }

    const size_t baseKV  = (size_t)bh * S_ * D_;
    const int    schunk  = S_ / NS;
    const int    ngroups = schunk / 32;

    f32x4 mpa[4][4];
    #pragma unroll
    for (int i = 0; i < 4; ++i)
    #pragma unroll
    for (int j = 0; j < 4; ++j) mpa[i][j] = fzero();
    float zacc[2][8];
    #pragma unroll
    for (int kk = 0; kk < 2; ++kk)
    #pragma unroll
    for (int j = 0; j < 8; ++j) zacc[kk][j] = 0.f;

    for (int g = wave; g < ngroups; g += 4) {
        const int row0 = p * schunk + g * 32;

        // ---- K rows -> sigma_k (B-frag-natural layout) ----
        float sk[2][2][8];
        #pragma unroll
        for (int st = 0; st < 2; ++st) {
            const float* kr = Kp + baseKV + (size_t)(row0 + st * 16 + c16) * D_;
            #pragma unroll
            for (int kk = 0; kk < 2; ++kk) {
                f32x4 a = *(const f32x4*)(kr + kk * 32 + g4 * 8);
                f32x4 b = *(const f32x4*)(kr + kk * 32 + g4 * 8 + 4);
                #pragma unroll
                for (int j = 0; j < 4; ++j) {
                    sk[st][kk][j]     = elup1(a[j]);
                    sk[st][kk][4 + j] = elup1(b[j]);
                }
            }
        }

        // ---- den = sigma_k . z0 (per row s = st*16 + c16) ----
        float den0 = 0.f, den1 = 0.f;
        #pragma unroll
        for (int kk = 0; kk < 2; ++kk)
        #pragma unroll
        for (int j = 0; j < 8; ++j) {
            den0 += sk[0][kk][j] * z0v[kk][j];
            den1 += sk[1][kk][j] * z0v[kk][j];
        }
        den0 += __shfl_xor(den0, 16); den0 += __shfl_xor(den0, 32);
        den1 += __shfl_xor(den1, 16); den1 += __shfl_xor(den1, 32);
        const float rd0 = __builtin_amdgcn_rcpf(den0 + EPS_);
        const float rd1 = __builtin_amdgcn_rcpf(den1 + EPS_);

        // ---- z partial ----
        #pragma unroll
        for (int kk = 0; kk < 2; ++kk)
        #pragma unroll
        for (int j = 0; j < 8; ++j) zacc[kk][j] += sk[0][kk][j] + sk[1][kk][j];

        // ---- bf16 frags + skT transpose write (packed st0|st1 in one b32) ----
        bf16x8 skf[2][2];
        #pragma unroll
        for (int kk = 0; kk < 2; ++kk)
        #pragma unroll
        for (int j = 0; j < 8; ++j) {
            unsigned short b0 = f2bf(sk[0][kk][j]);
            unsigned short b1 = f2bf(sk[1][kk][j]);
            skf[0][kk][j] = (short)b0;
            skf[1][kk][j] = (short)b1;
            *(unsigned*)&skT[wave][kk * 32 + g4 * 8 + j][2 * c16] =
                (unsigned)b0 | ((unsigned)b1 << 16);
        }

        // ---- GEMM1^T: NUM^T tiles; lane gets NUM[s=st*16+c16][e=et*16+g4*4+r] ----
        f32x4 acc[2][4];
        #pragma unroll
        for (int st = 0; st < 2; ++st)
        #pragma unroll
        for (int et = 0; et < 4; ++et) {
            f32x4 t = __builtin_amdgcn_mfma_f32_16x16x32_bf16(w0f[et][0], skf[st][0], fzero(), 0, 0, 0);
            acc[st][et] = __builtin_amdgcn_mfma_f32_16x16x32_bf16(w0f[et][1], skf[st][1], t, 0, 0, 0);
        }

        // ---- VU = V - NUM/den; write vuT (packed st0|st1 b32) ----
        const float* vr0 = Vp + baseKV + (size_t)(row0 + c16) * D_;
        const float* vr1 = Vp + baseKV + (size_t)(row0 + 16 + c16) * D_;
        #pragma unroll
        for (int et = 0; et < 4; ++et) {
            f32x4 v0 = *(const f32x4*)(vr0 + et * 16 + g4 * 4);
            f32x4 v1 = *(const f32x4*)(vr1 + et * 16 + g4 * 4);
            #pragma unroll
            for (int r = 0; r < 4; ++r) {
                float u0 = v0[r] - acc[0][et][r] * rd0;
                float u1 = v1[r] - acc[1][et][r] * rd1;
                *(unsigned*)&vuT[wave][et * 16 + g4 * 4 + r][2 * c16] =
                    (unsigned)f2bf(u0) | ((unsigned)f2bf(u1) << 16);
            }
        }

        // ---- GEMM2: MP += SK^T @ VU (K=32 via permuted columns; wave-private LDS,
        //      no barrier needed: compiler orders same-wave DS ops via lgkmcnt) ----
        bf16x8 am[4], bn[4];
        #pragma unroll
        for (int mt = 0; mt < 4; ++mt)
            am[mt] = *(const bf16x8*)&skT[wave][mt * 16 + c16][g4 * 8];
        #pragma unroll
        for (int nt = 0; nt < 4; ++nt)
            bn[nt] = *(const bf16x8*)&vuT[wave][nt * 16 + c16][g4 * 8];
        #pragma unroll
        for (int mt = 0; mt < 4; ++mt)
        #pragma unroll
        for (int nt = 0; nt < 4; ++nt)
            mpa[mt][nt] = __builtin_amdgcn_mfma_f32_16x16x32_bf16(am[mt], bn[nt], mpa[mt][nt], 0, 0, 0);
    }

    // ---- z: reduce across c16 lanes, writer lanes c16==0 cover d = kk*32+g4*8+j ----
    #pragma unroll
    for (int kk = 0; kk < 2; ++kk)
    #pragma unroll
    for (int j = 0; j < 8; ++j) {
        float z = zacc[kk][j];
        z += __shfl_xor(z, 1); z += __shfl_xor(z, 2);
        z += __shfl_xor(z, 4); z += __shfl_xor(z, 8);
        if (c16 == 0) Zlds[wave][kk * 32 + g4 * 8 + j] = z;
    }

    // ---- serial deterministic cross-wave MP reduce in LDS ----
    __syncthreads();
    for (int w = 0; w < 4; ++w) {
        if (wave == w) {
            #pragma unroll
            for (int mt = 0; mt < 4; ++mt)
            #pragma unroll
            for (int nt = 0; nt < 4; ++nt)
            #pragma unroll
            for (int r = 0; r < 4; ++r) {
                int idx = (mt * 16 + g4 * 4 + r) * 65 + nt * 16 + c16;
                float v = mpa[mt][nt][r];
                Mlds[idx] = (w == 0) ? v : (Mlds[idx] + v);
            }
        }
        __syncthreads();
    }

    float* mout = Mpart + ((size_t)p * BH_ + bh) * 4096;
    #pragma unroll
    for (int i = 0; i < 16; ++i) {
        int idx = i * 256 + tid;
        mout[idx] = Mlds[(idx >> 6) * 65 + (idx & 63)];
    }
    if (tid < 64) {
        float zs = Zlds[0][tid] + Zlds[1][tid] + Zlds[2][tid] + Zlds[3][tid];
        Zpart[((size_t)p * BH_ + bh) * 64 + tid] = zs;
    }
}

// ---------------------------------------------------------------------------
// Reduce: M_final = W0 + sum_p Mpart ; z_final = z0 + sum_p Zpart
// ---------------------------------------------------------------------------
__global__ void k_reduce(const float* __restrict__ Mpart, const float* __restrict__ Zpart,
                         const float* __restrict__ W0, const float* __restrict__ Z0,
                         float* __restrict__ Mfin, float* __restrict__ Zfin, int NS)
{
    const int bh = blockIdx.x, h = bh & (H_ - 1), t = threadIdx.x;
    #pragma unroll
    for (int i = 0; i < 4; ++i) {
        int fi = i * 256 + t;  // float4 index within 4096
        f32x4 s = *(const f32x4*)(W0 + (size_t)h * 4096 + fi * 4);
        for (int p = 0; p < NS; ++p) {
            f32x4 v = *(const f32x4*)(Mpart + ((size_t)p * BH_ + bh) * 4096 + fi * 4);
            s = s + v;
        }
        *(f32x4*)(Mfin + (size_t)bh * 4096 + fi * 4) = s;
    }
    if (t < 64) {
        float s = Z0[h * 64 + t];
        for (int p = 0; p < NS; ++p) s += Zpart[((size_t)p * BH_ + bh) * 64 + t];
        Zfin[bh * 64 + t] = s;
    }
}

// ---------------------------------------------------------------------------
// Kernel 2: RET^T = M^T @ SQ^T ; out = O + gate*(RET/norm - O). No LDS.
// ---------------------------------------------------------------------------
__global__ __launch_bounds__(256, 2) void k2_out(
    const float* __restrict__ Qp, const float* __restrict__ Op,
    const float* __restrict__ Bp, const float* __restrict__ Mfin,
    const float* __restrict__ Zfin, float* __restrict__ Out, int NS2)
{
    const int bh = blockIdx.x / NS2;
    const int p  = blockIdx.x % NS2;
    const int h  = bh & (H_ - 1);
    const int tid = threadIdx.x, lane = tid & 63, wave = tid >> 6;
    const int c16 = lane & 15, g4 = lane >> 4;

    float mzv[2][8];
    #pragma unroll
    for (int kk = 0; kk < 2; ++kk) {
        f32x4 a = *(const f32x4*)(Zfin + bh * 64 + kk * 32 + g4 * 8);
        f32x4 b = *(const f32x4*)(Zfin + bh * 64 + kk * 32 + g4 * 8 + 4);
        #pragma unroll
        for (int j = 0; j < 4; ++j) { mzv[kk][j] = a[j]; mzv[kk][4 + j] = b[j]; }
    }

    bf16x8 mf[4][2];  // M^T A-frags: A[e][d] = M[d][e]
    #pragma unroll
    for (int et = 0; et < 4; ++et)
    #pragma unroll
    for (int kk = 0; kk < 2; ++kk) {
        bf16x8 f;
        #pragma unroll
        for (int j = 0; j < 8; ++j)
            f[j] = (short)f2bf(Mfin[(size_t)bh * 4096 + (kk * 32 + g4 * 8 + j) * 64 + et * 16 + c16]);
        mf[et][kk] = f;
    }

    float gate[4][4];
    #pragma unroll
    for (int et = 0; et < 4; ++et)
    #pragma unroll
    for (int r = 0; r < 4; ++r) {
        float b = Bp[h * 64 + et * 16 + g4 * 4 + r];
        gate[et][r] = 1.0f / (1.0f + __expf(-b));
    }

    const size_t base = (size_t)bh * S_ * D_;
    const int schunk = S_ / NS2, ngroups = schunk / 32;

    for (int g = wave; g < ngroups; g += 4) {
        const int row0 = p * schunk + g * 32;

        float sq[2][2][8];
        #pragma unroll
        for (int st = 0; st < 2; ++st) {
            const float* qr = Qp + base + (size_t)(row0 + st * 16 + c16) * D_;
            #pragma unroll
            for (int kk = 0; kk < 2; ++kk) {
                f32x4 a = *(const f32x4*)(qr + kk * 32 + g4 * 8);
                f32x4 b = *(const f32x4*)(qr + kk * 32 + g4 * 8 + 4);
                #pragma unroll
                for (int j = 0; j < 4; ++j) {
                    sq[st][kk][j]     = elup1(a[j]);
                    sq[st][kk][4 + j] = elup1(b[j]);
                }
            }
        }

        float n0 = 0.f, n1 = 0.f;
        #pragma unroll
        for (int kk = 0; kk < 2; ++kk)
        #pragma unroll
        for (int j = 0; j < 8; ++j) {
            n0 += sq[0][kk][j] * mzv[kk][j];
            n1 += sq[1][kk][j] * mzv[kk][j];
        }
        n0 += __shfl_xor(n0, 16); n0 += __shfl_xor(n0, 32);
        n1 += __shfl_xor(n1, 16); n1 += __shfl_xor(n1, 32);
        const float rn0 = __builtin_amdgcn_rcpf(n0 + EPS_);
        const float rn1 = __builtin_amdgcn_rcpf(n1 + EPS_);

        bf16x8 sqf[2][2];
        #pragma unroll
        for (int st = 0; st < 2; ++st)
        #pragma unroll
        for (int kk = 0; kk < 2; ++kk) {
            bf16x8 f;
            #pragma unroll
            for (int j = 0; j < 8; ++j) f[j] = (short)f2bf(sq[st][kk][j]);
            sqf[st][kk] = f;
        }

        f32x4 acc[2][4];
        #pragma unroll
        for (int st = 0; st < 2; ++st)
        #pragma unroll
        for (int et = 0; et < 4; ++et) {
            f32x4 t = __builtin_amdgcn_mfma_f32_16x16x32_bf16(mf[et][0], sqf[st][0], fzero(), 0, 0, 0);
            acc[st][et] = __builtin_amdgcn_mfma_f32_16x16x32_bf16(mf[et][1], sqf[st][1], t, 0, 0, 0);
        }

        #pragma unroll
        for (int st = 0; st < 2; ++st) {
            const float rn = st ? rn1 : rn0;
            const size_t roff = base + (size_t)(row0 + st * 16 + c16) * D_;
            #pragma unroll
            for (int et = 0; et < 4; ++et) {
                f32x4 o4 = *(const f32x4*)(Op + roff + et * 16 + g4 * 4);
                f32x4 w;
                #pragma unroll
                for (int r = 0; r < 4; ++r) {
                    float t = acc[st][et][r] * rn;
                    w[r] = o4[r] + gate[et][r] * (t - o4[r]);
                }
                *(f32x4*)(Out + roff + et * 16 + g4 * 4) = w;
            }
        }
    }
}

// ---------------------------------------------------------------------------
extern "C" void kernel_launch(void* const* d_in, const int* in_sizes, int n_in,
                              void* d_out, int out_size, void* d_ws, size_t ws_size,
                              hipStream_t stream)
{
    const float* Q  = (const float*)d_in[0];
    const float* K  = (const float*)d_in[1];
    const float* V  = (const float*)d_in[2];
    const float* O  = (const float*)d_in[3];
    const float* Bt = (const float*)d_in[4];
    const float* W0 = (const float*)d_in[5];
    const float* Z0 = (const float*)d_in[6];
    float* Out = (float*)d_out;

    // workspace: [Mpart NS*64*4096][Zpart NS*64*64][Mfin 64*4096][Zfin 64*64] (f32)
    int NS = 8;
    auto need = [](int ns) -> size_t {
        return sizeof(float) * ((size_t)ns * BH_ * 4096 + (size_t)ns * BH_ * 64 +
                                (size_t)BH_ * 4096 + (size_t)BH_ * 64);
    };
    while (NS > 1 && need(NS) > ws_size) NS >>= 1;

    float* Mpart = (float*)d_ws;
    float* Zpart = Mpart + (size_t)NS * BH_ * 4096;
    float* Mfin  = Zpart + (size_t)NS * BH_ * 64;
    float* Zfin  = Mfin + (size_t)BH_ * 4096;

    hipLaunchKernelGGL(k1_states, dim3(BH_ * NS), dim3(256), 0, stream,
                       K, V, W0, Z0, Mpart, Zpart, NS);
    hipLaunchKernelGGL(k_reduce, dim3(BH_), dim3(256), 0, stream,
                       Mpart, Zpart, W0, Z0, Mfin, Zfin, NS);
    hipLaunchKernelGGL(k2_out, dim3(BH_ * 8), dim3(256), 0, stream,
                       Q, O, Bt, Mfin, Zfin, Out, 8);
}